// Round 5
// baseline (107.514 us; speedup 1.0000x reference)
//
#include <hip/hip_runtime.h>

typedef __attribute__((ext_vector_type(8))) short short8;
typedef __attribute__((ext_vector_type(4))) float f32x4;

// Problem constants
constexpr int B_ = 8, IN_C_ = 64, IN_L_ = 64, T_ = 256, OUT_C_ = 64, OUT_L_ = 64;
constexpr float EPS_ = 1e-5f;

// xT_pad: bf16 [8 b][66 lp][258 tp][64 ic]; lp = l+1, tp = t+1, halo rows/cols = 0
constexpr int XT_LP = 66, XT_TP = 258, XT_IC = 64;
constexpr int XT_LSTRIDE = XT_TP * XT_IC;            // 16512 elems
constexpr int XT_BSTRIDE = XT_LP * XT_LSTRIDE;       // 1,089,792 elems
constexpr size_t XT_ELEMS = (size_t)B_ * XT_BSTRIDE; // 8,718,336
constexpr size_t XT_BYTES = XT_ELEMS * 2;            // 17,436,672
// wT2: bf16 [64 l][9 tap][64 c][64 ic]
constexpr size_t WT2_ELEMS = 64ull * 9 * 64 * 64;    // 2,359,296
constexpr size_t WT2_OFF_B = XT_BYTES;
constexpr size_t PART_OFF_B = WT2_OFF_B + WT2_ELEMS * 2;    // 22,155,264
constexpr size_t SS_OFF_B = PART_OFF_B + 1024ull * 128 * 4; // 22,679,552
constexpr size_t WS_NEED = SS_OFF_B + 128 * 4;              // 22,680,064

__device__ __forceinline__ unsigned short f2bf(float f) {
  unsigned u = __float_as_uint(f);
  return (unsigned short)((u + 0x7fffu + ((u >> 16) & 1u)) >> 16);
}

// ---------------------------------------------------------------------------
// Prepass 1: x fp32 [b][ic][l][t] -> xT bf16 [b][l+1][t+1][ic] (LDS transpose).
// grid = 8*64*2 = 1024 blocks; block (b, l, t-half of 128). Interior only.
// ---------------------------------------------------------------------------
__global__ __launch_bounds__(256) void xprep(const float* __restrict__ x,
                                             unsigned short* __restrict__ xT) {
  const int bid = blockIdx.x;
  const int th = bid & 1, l = (bid >> 1) & 63, b = bid >> 7;
  const int tid = threadIdx.x;
  const int t0 = th * 128;
  __shared__ unsigned short ls[64][132];  // [ic][t-local], pad keeps rows 8B-aligned
  {
    const int ic = tid >> 2, q = tid & 3;
    const float4* src = (const float4*)(x + (((size_t)(b * 64 + ic) * 64 + l) * 256 + t0));
#pragma unroll
    for (int e = 0; e < 8; ++e) {
      float4 v = src[q * 8 + e];
      const int toff = (q * 8 + e) * 4;
      unsigned d0 = f2bf(v.x) | ((unsigned)f2bf(v.y) << 16);
      unsigned d1 = f2bf(v.z) | ((unsigned)f2bf(v.w) << 16);
      *(uint2*)&ls[ic][toff] = make_uint2(d0, d1);
    }
  }
  __syncthreads();
  {
    const int tl = tid >> 1, h = tid & 1;  // t-row, ic-half
    unsigned d[16];
#pragma unroll
    for (int k = 0; k < 16; ++k) {
      unsigned short a = ls[h * 32 + 2 * k][tl];
      unsigned short c = ls[h * 32 + 2 * k + 1][tl];
      d[k] = a | ((unsigned)c << 16);
    }
    unsigned short* dst =
        xT + ((size_t)(b * XT_LP + l + 1) * XT_TP + (t0 + tl + 1)) * XT_IC + h * 32;
    uint4* dv = (uint4*)dst;
    dv[0] = make_uint4(d[0], d[1], d[2], d[3]);
    dv[1] = make_uint4(d[4], d[5], d[6], d[7]);
    dv[2] = make_uint4(d[8], d[9], d[10], d[11]);
    dv[3] = make_uint4(d[12], d[13], d[14], d[15]);
  }
}

// ---------------------------------------------------------------------------
// Prepass 2 (merged): blocks [0,144): w fp32 [k=ic*9+tap][c][l] -> wT2 bf16
// [l][tap][c][ic]. Blocks [144,152): zero xT halo (lp=0/65 planes, tp=0/257
// columns) for batch b = bid-144. Replaces the 17.4 MB memset (663 KB).
// ---------------------------------------------------------------------------
__global__ __launch_bounds__(256) void wprep_halo(const float* __restrict__ w,
                                                  unsigned short* __restrict__ wT2,
                                                  unsigned short* __restrict__ xT) {
  const int bid = blockIdx.x;
  if (bid < 144) {
    const int g = bid * 256 + threadIdx.x;  // 0..36863
    const int c = g & 63;
    const int lt = g >> 6;  // l*9 + tap, 0..575
    const int l = lt / 9;
    const int tap = lt % 9;
    unsigned short* dst = wT2 + ((size_t)lt * 64 + c) * 64;
    const float* src = w + ((size_t)tap * 64 + c) * 64 + l;  // + ic*9*4096
#pragma unroll
    for (int ic0 = 0; ic0 < 64; ic0 += 8) {
      unsigned d[4];
#pragma unroll
      for (int k = 0; k < 4; ++k) {
        float a = src[(size_t)(ic0 + 2 * k) * 9 * 4096];
        float c2 = src[(size_t)(ic0 + 2 * k + 1) * 9 * 4096];
        d[k] = f2bf(a) | ((unsigned)f2bf(c2) << 16);
      }
      *(uint4*)(dst + ic0) = make_uint4(d[0], d[1], d[2], d[3]);
    }
  } else {
    const int b = bid - 144;  // 0..7
    unsigned short* base = xT + (size_t)b * XT_BSTRIDE;
    const short8 z = {};
    // 16B chunks: 2 lp-planes (2*2064) + tp columns (66 lp * 2 cols * 8)
    for (int ci = threadIdx.x; ci < 5184; ci += 256) {
      size_t off;
      if (ci < 4128) {
        const int plane = ci / 2064, k = ci % 2064;
        off = (size_t)(plane ? 65 : 0) * XT_LSTRIDE + (size_t)k * 8;
      } else {
        const int k = ci - 4128;            // 0..1055
        const int lp = k >> 4, rem = k & 15;
        const int tp = (rem < 8) ? 0 : 257;
        off = ((size_t)lp * XT_TP + tp) * 64 + (size_t)(rem & 7) * 8;
      }
      *(short8*)(base + off) = z;
    }
  }
}

// ---------------------------------------------------------------------------
// Main conv: block = (b, l, t-half), 4 waves; wave = 32 t-rows x 64 c
// (2 m-frags x 4 n-frags of mfma_f32_16x16x32_bf16), K=576 via 18 steps.
// Depth-2 register prefetch (3 rotating buffers). XCD swizzle: each XCD owns
// one batch b (xT slice 2.2 MB -> L2-resident per XCD).
// Epilogue: bias add, float4 store, fused per-channel sum/sumsq partials.
// ---------------------------------------------------------------------------
__global__ __launch_bounds__(256, 4) void conv_mfma(
    const unsigned short* __restrict__ xT, const unsigned short* __restrict__ wT2,
    const float* __restrict__ bias, float* __restrict__ out,
    float* __restrict__ part) {
  const int orig = blockIdx.x;                    // 0..1023
  const int wg = (orig & 7) * 128 + (orig >> 3);  // XCD x -> b = x
  const int th = wg & 1, l = (wg >> 1) & 63, b = wg >> 7;
  const int tid = threadIdx.x;
  const int wid = tid >> 6, ln = tid & 63;
  const int lc = ln & 15, lg = ln >> 4;
  const int m0 = th * 128 + wid * 32;

  const unsigned short* xA = xT + (size_t)(b * XT_LP + l) * XT_LSTRIDE + lg * 8;
  const unsigned short* wB = wT2 + (size_t)l * 9 * 4096 + lc * 64 + lg * 8;

  int aoff[2];
#pragma unroll
  for (int mi = 0; mi < 2; ++mi) aoff[mi] = (m0 + mi * 16 + lc) * XT_IC;

  f32x4 acc[2][4] = {};
  short8 ab[3][2], bb[3][4];

  auto LOADS = [&](int buf, int s) {
    const int tap = s >> 1, kb = s & 1, ii = tap / 3, jj = tap % 3;
#pragma unroll
    for (int mi = 0; mi < 2; ++mi)
      ab[buf][mi] = *(const short8*)(xA + aoff[mi] + jj * XT_IC + ii * XT_LSTRIDE + kb * 32);
#pragma unroll
    for (int ni = 0; ni < 4; ++ni)
      bb[buf][ni] = *(const short8*)(wB + tap * 4096 + ni * 1024 + kb * 32);
  };

  LOADS(0, 0);
  LOADS(1, 1);
#pragma unroll
  for (int step = 0; step < 18; ++step) {
    if (step + 2 < 18) LOADS((step + 2) % 3, step + 2);
    const int cur = step % 3;
#pragma unroll
    for (int mi = 0; mi < 2; ++mi)
#pragma unroll
      for (int ni = 0; ni < 4; ++ni)
        acc[mi][ni] =
            __builtin_amdgcn_mfma_f32_16x16x32_bf16(ab[cur][mi], bb[cur][ni], acc[mi][ni], 0, 0, 0);
  }

  // epilogue: bias + store + fused stats. D: row(t)=m0+mi*16+lg*4+r, col(c)=ni*16+lc
  __shared__ float sm[4][4][16][2];
#pragma unroll
  for (int ni = 0; ni < 4; ++ni) {
    const int c = ni * 16 + lc;
    const float bv = bias[c * 64 + l];
    float s = 0.f, s2 = 0.f;
    float* op = out + ((size_t)(b * 64 + c) * 64 + l) * 256 + m0;
#pragma unroll
    for (int mi = 0; mi < 2; ++mi) {
      float4 vv;
#pragma unroll
      for (int r = 0; r < 4; ++r) {
        float v = acc[mi][ni][r] + bv;
        ((float*)&vv)[r] = v;
        s += v;
        s2 += v * v;
      }
      *(float4*)(op + mi * 16 + lg * 4) = vv;
    }
    s += __shfl_xor(s, 16);  s += __shfl_xor(s, 32);
    s2 += __shfl_xor(s2, 16); s2 += __shfl_xor(s2, 32);
    if (lg == 0) { sm[wid][ni][lc][0] = s; sm[wid][ni][lc][1] = s2; }
  }
  __syncthreads();
  if (tid < 128) {
    const int sel = tid >> 6, cc = tid & 63;
    const int ni = cc >> 4, lc2 = cc & 15;
    part[(size_t)wg * 128 + sel * 64 + cc] =
        sm[0][ni][lc2][sel] + sm[1][ni][lc2][sel] + sm[2][ni][lc2][sel] + sm[3][ni][lc2][sel];
  }
}

// ---------------------------------------------------------------------------
// Finalize per-channel scale/shift from 1024 block-partials.
// ---------------------------------------------------------------------------
__global__ __launch_bounds__(256) void stats_final_mf(
    const float* __restrict__ part, const float* __restrict__ gamma,
    const float* __restrict__ beta, float* __restrict__ ss) {
  const int c = blockIdx.x;  // 0..63
  const int tid = threadIdx.x;
  float s = 0.f, s2 = 0.f;
  for (int blk = tid; blk < 1024; blk += 256) {
    s += part[(size_t)blk * 128 + c];
    s2 += part[(size_t)blk * 128 + 64 + c];
  }
#pragma unroll
  for (int off = 32; off; off >>= 1) {
    s += __shfl_down(s, off);
    s2 += __shfl_down(s2, off);
  }
  __shared__ float r0[4], r1[4];
  const int wid = tid >> 6, lane = tid & 63;
  if (lane == 0) { r0[wid] = s; r1[wid] = s2; }
  __syncthreads();
  if (tid == 0) {
    float S = r0[0] + r0[1] + r0[2] + r0[3];
    float S2 = r1[0] + r1[1] + r1[2] + r1[3];
    const float inv_n = 1.0f / 131072.f;
    float mean = S * inv_n;
    float var = S2 * inv_n - mean * mean;
    float inv = rsqrtf(var + EPS_);
    float sc = gamma[c] * inv;
    ss[c] = sc;
    ss[64 + c] = beta[c] - mean * sc;
  }
}

// ---------------------------------------------------------------------------
// BN apply + PReLU, in place, float4 vectorized.
// ---------------------------------------------------------------------------
__global__ __launch_bounds__(256) void bn_prelu(
    float* __restrict__ out, const float* __restrict__ scaleshift,
    const float* __restrict__ alpha) {
  const float a = alpha[0];
  constexpr size_t N4 = (size_t)B_ * OUT_C_ * OUT_L_ * T_ / 4;  // 2097152
  float4* p = (float4*)out;
  for (size_t i = (size_t)blockIdx.x * 256 + threadIdx.x; i < N4;
       i += (size_t)gridDim.x * 256) {
    const int c = (int)((i >> 12) & 63);
    const float sc = scaleshift[c];
    const float sh = scaleshift[64 + c];
    float4 v = p[i];
    v.x = v.x * sc + sh; v.x = (v.x >= 0.f) ? v.x : a * v.x;
    v.y = v.y * sc + sh; v.y = (v.y >= 0.f) ? v.y : a * v.y;
    v.z = v.z * sc + sh; v.z = (v.z >= 0.f) ? v.z : a * v.z;
    v.w = v.w * sc + sh; v.w = (v.w >= 0.f) ? v.w : a * v.w;
    p[i] = v;
  }
}

// ======================= Fallback (round-2 VALU path) =======================
__global__ __launch_bounds__(256) void conv_fb(
    const float* __restrict__ x, const float* __restrict__ w,
    const float* __restrict__ bias, float* __restrict__ out,
    float* __restrict__ part) {
  const int bid = blockIdx.x;
  const int cg = bid & 3;
  const int l = (bid >> 2) & 63;
  const int b = bid >> 8;
  const int t = threadIdx.x;
  const int cbase = cg * 16;
  __shared__ float lw[576 * 16];
  for (int idx = t; idx < 576 * 16; idx += 256) {
    const int k = idx >> 4, cl = idx & 15;
    lw[idx] = w[((size_t)(k * OUT_C_ + cbase + cl)) * OUT_L_ + l];
  }
  __syncthreads();
  float acc[16];
#pragma unroll
  for (int c = 0; c < 16; ++c) acc[c] = 0.f;
  const bool l0 = (l >= 1), l2 = (l + 1 < IN_L_);
  const bool t0 = (t >= 1), t2 = (t + 1 < T_);
  for (int ic = 0; ic < IN_C_; ++ic) {
    const float* xr = x + (((size_t)(b * IN_C_ + ic)) * IN_L_ + l) * T_ + t;
    float xv[9];
    xv[0] = (l0 && t0) ? xr[-T_ - 1] : 0.f;
    xv[1] = l0 ? xr[-T_] : 0.f;
    xv[2] = (l0 && t2) ? xr[-T_ + 1] : 0.f;
    xv[3] = t0 ? xr[-1] : 0.f;
    xv[4] = xr[0];
    xv[5] = t2 ? xr[1] : 0.f;
    xv[6] = (l2 && t0) ? xr[T_ - 1] : 0.f;
    xv[7] = l2 ? xr[T_] : 0.f;
    xv[8] = (l2 && t2) ? xr[T_ + 1] : 0.f;
    const int base = ic * 9 * 16;
#pragma unroll
    for (int kk = 0; kk < 9; ++kk) {
      const float xvk = xv[kk];
      const float* wk = &lw[base + kk * 16];
#pragma unroll
      for (int c = 0; c < 16; ++c) acc[c] = fmaf(xvk, wk[c], acc[c]);
    }
  }
  const int wid = t >> 6, lane = t & 63;
  __shared__ float ls[4][16], ls2[4][16];
  const size_t obase = (((size_t)(b * OUT_C_ + cbase)) * OUT_L_ + l) * T_ + t;
#pragma unroll
  for (int c = 0; c < 16; ++c) {
    float v = acc[c] + bias[(cbase + c) * OUT_L_ + l];
    out[obase + (size_t)c * (OUT_L_ * T_)] = v;
    float s = v, s2 = v * v;
#pragma unroll
    for (int off = 32; off; off >>= 1) {
      s += __shfl_down(s, off);
      s2 += __shfl_down(s2, off);
    }
    if (lane == 0) { ls[wid][c] = s; ls2[wid][c] = s2; }
  }
  __syncthreads();
  if (t < 16) {
    part[(size_t)bid * 32 + t] = ls[0][t] + ls[1][t] + ls[2][t] + ls[3][t];
  } else if (t < 32) {
    const int c = t - 16;
    part[(size_t)bid * 32 + 16 + c] = ls2[0][c] + ls2[1][c] + ls2[2][c] + ls2[3][c];
  }
}

__global__ __launch_bounds__(64) void stats_final_fb(
    const float* __restrict__ part, const float* __restrict__ gamma,
    const float* __restrict__ beta, float* __restrict__ scaleshift) {
  const int C = blockIdx.x;
  const int cg = C >> 4, cloc = C & 15;
  const int t = threadIdx.x;
  float s = 0.f, s2 = 0.f;
  for (int i = t; i < 512; i += 64) {
    const int b = i >> 6, l = i & 63;
    const size_t idx = ((size_t)(b * 256 + l * 4 + cg)) * 32;
    s += part[idx + cloc];
    s2 += part[idx + 16 + cloc];
  }
#pragma unroll
  for (int off = 32; off; off >>= 1) {
    s += __shfl_down(s, off);
    s2 += __shfl_down(s2, off);
  }
  if (t == 0) {
    const float inv_n = 1.0f / (float)(B_ * OUT_L_ * T_);
    const float mean = s * inv_n;
    const float var = s2 * inv_n - mean * mean;
    const float inv = rsqrtf(var + EPS_);
    const float sc = gamma[C] * inv;
    scaleshift[C] = sc;
    scaleshift[64 + C] = beta[C] - mean * sc;
  }
}

extern "C" void kernel_launch(void* const* d_in, const int* in_sizes, int n_in,
                              void* d_out, int out_size, void* d_ws, size_t ws_size,
                              hipStream_t stream) {
  const float* x = (const float*)d_in[0];
  const float* w = (const float*)d_in[1];
  const float* bias = (const float*)d_in[2];
  const float* gamma = (const float*)d_in[3];
  const float* beta = (const float*)d_in[4];
  const float* alpha = (const float*)d_in[5];
  float* out = (float*)d_out;

  if (ws_size >= WS_NEED) {
    unsigned short* xT = (unsigned short*)d_ws;
    unsigned short* wT2 = (unsigned short*)((char*)d_ws + WT2_OFF_B);
    float* part = (float*)((char*)d_ws + PART_OFF_B);
    float* ssb = (float*)((char*)d_ws + SS_OFF_B);
    xprep<<<dim3(1024), dim3(256), 0, stream>>>(x, xT);
    wprep_halo<<<dim3(152), dim3(256), 0, stream>>>(w, wT2, xT);
    conv_mfma<<<dim3(1024), dim3(256), 0, stream>>>(xT, wT2, bias, out, part);
    stats_final_mf<<<dim3(64), dim3(256), 0, stream>>>(part, gamma, beta, ssb);
    bn_prelu<<<dim3(2048), dim3(256), 0, stream>>>(out, ssb, alpha);
  } else {
    float* ws = (float*)d_ws;
    float* part = ws;
    float* ss = ws + 65536;
    conv_fb<<<dim3(B_ * OUT_L_ * 4), dim3(256), 0, stream>>>(x, w, bias, out, part);
    stats_final_fb<<<dim3(64), dim3(64), 0, stream>>>(part, gamma, beta, ss);
    bn_prelu<<<dim3(2048), dim3(256), 0, stream>>>(out, ss, alpha);
  }
}

// Round 6
// 68.757 us; speedup vs baseline: 1.5637x; 1.5637x over previous
//
#include <hip/hip_runtime.h>

typedef __attribute__((ext_vector_type(8))) short short8;
typedef __attribute__((ext_vector_type(4))) float f32x4;

// Problem constants
constexpr int B_ = 8, IN_C_ = 64, IN_L_ = 64, T_ = 256, OUT_C_ = 64, OUT_L_ = 64;
constexpr float EPS_ = 1e-5f;

// xT_pad: bf16 [8 b][66 lp][258 tp][64 ic]; lp = l+1, tp = t+1, halo rows/cols = 0
constexpr int XT_LP = 66, XT_TP = 258, XT_IC = 64;
constexpr int XT_LSTRIDE = XT_TP * XT_IC;            // 16512 elems
constexpr int XT_BSTRIDE = XT_LP * XT_LSTRIDE;       // 1,089,792 elems
constexpr size_t XT_ELEMS = (size_t)B_ * XT_BSTRIDE; // 8,718,336
constexpr size_t XT_BYTES = XT_ELEMS * 2;            // 17,436,672
// wT2: bf16 [64 l][9 tap][64 c][64 ic]
constexpr size_t WT2_ELEMS = 64ull * 9 * 64 * 64;    // 2,359,296
constexpr size_t WT2_OFF_B = XT_BYTES;
constexpr size_t PART_OFF_B = WT2_OFF_B + WT2_ELEMS * 2;   // 22,155,264
constexpr size_t SS_OFF_B = PART_OFF_B + 512ull * 128 * 4; // 22,417,408
constexpr size_t WS_NEED = SS_OFF_B + 128 * 4;             // 22,417,920

__device__ __forceinline__ unsigned short f2bf(float f) {
  unsigned u = __float_as_uint(f);
  return (unsigned short)((u + 0x7fffu + ((u >> 16) & 1u)) >> 16);
}

__device__ __forceinline__ void gload_lds16(const void* g, void* l) {
  __builtin_amdgcn_global_load_lds(
      (const __attribute__((address_space(1))) unsigned int*)g,
      (__attribute__((address_space(3))) unsigned int*)l, 16, 0, 0);
}

// ---------------------------------------------------------------------------
// Fused prep kernel. Blocks [0,1024): xprep — x fp32 [b][ic][l][t] -> xT bf16
// [b][l+1][t+1][ic] (LDS transpose). Blocks [1024,1168): wprep — w fp32
// [k=ic*9+tap][c][l] -> wT2 bf16 [l][tap][c][ic]. Blocks [1168,1176): zero
// the xT halo (663 KB) for batch b = bid-1168.
// ---------------------------------------------------------------------------
__global__ __launch_bounds__(256) void prep_kernel(const float* __restrict__ x,
                                                   const float* __restrict__ w,
                                                   unsigned short* __restrict__ xT,
                                                   unsigned short* __restrict__ wT2) {
  const int bid = blockIdx.x;
  const int tid = threadIdx.x;
  if (bid < 1024) {
    const int th = bid & 1, l = (bid >> 1) & 63, b = bid >> 7;
    const int t0 = th * 128;
    __shared__ unsigned short ls[64][132];  // [ic][t-local], pad keeps rows 8B-aligned
    {
      const int ic = tid >> 2, q = tid & 3;
      const float4* src = (const float4*)(x + (((size_t)(b * 64 + ic) * 64 + l) * 256 + t0));
#pragma unroll
      for (int e = 0; e < 8; ++e) {
        float4 v = src[q * 8 + e];
        const int toff = (q * 8 + e) * 4;
        unsigned d0 = f2bf(v.x) | ((unsigned)f2bf(v.y) << 16);
        unsigned d1 = f2bf(v.z) | ((unsigned)f2bf(v.w) << 16);
        *(uint2*)&ls[ic][toff] = make_uint2(d0, d1);
      }
    }
    __syncthreads();
    {
      const int tl = tid >> 1, h = tid & 1;  // t-row, ic-half
      unsigned d[16];
#pragma unroll
      for (int k = 0; k < 16; ++k) {
        unsigned short a = ls[h * 32 + 2 * k][tl];
        unsigned short c = ls[h * 32 + 2 * k + 1][tl];
        d[k] = a | ((unsigned)c << 16);
      }
      unsigned short* dst =
          xT + ((size_t)(b * XT_LP + l + 1) * XT_TP + (t0 + tl + 1)) * XT_IC + h * 32;
      uint4* dv = (uint4*)dst;
      dv[0] = make_uint4(d[0], d[1], d[2], d[3]);
      dv[1] = make_uint4(d[4], d[5], d[6], d[7]);
      dv[2] = make_uint4(d[8], d[9], d[10], d[11]);
      dv[3] = make_uint4(d[12], d[13], d[14], d[15]);
    }
  } else if (bid < 1168) {
    const int g = (bid - 1024) * 256 + tid;  // 0..36863
    const int c = g & 63;
    const int lt = g >> 6;  // l*9 + tap, 0..575
    const int l = lt / 9;
    const int tap = lt % 9;
    unsigned short* dst = wT2 + ((size_t)lt * 64 + c) * 64;
    const float* src = w + ((size_t)tap * 64 + c) * 64 + l;  // + ic*9*4096
#pragma unroll
    for (int ic0 = 0; ic0 < 64; ic0 += 8) {
      unsigned d[4];
#pragma unroll
      for (int k = 0; k < 4; ++k) {
        float a = src[(size_t)(ic0 + 2 * k) * 9 * 4096];
        float c2 = src[(size_t)(ic0 + 2 * k + 1) * 9 * 4096];
        d[k] = f2bf(a) | ((unsigned)f2bf(c2) << 16);
      }
      *(uint4*)(dst + ic0) = make_uint4(d[0], d[1], d[2], d[3]);
    }
  } else {
    const int b = bid - 1168;  // 0..7
    unsigned short* base = xT + (size_t)b * XT_BSTRIDE;
    const short8 z = {};
    // 16B chunks: 2 lp-planes (2*2064) + tp columns (66 lp * 2 cols * 8)
    for (int ci = tid; ci < 5184; ci += 256) {
      size_t off;
      if (ci < 4128) {
        const int plane = ci / 2064, k = ci % 2064;
        off = (size_t)(plane ? 65 : 0) * XT_LSTRIDE + (size_t)k * 8;
      } else {
        const int k = ci - 4128;            // 0..1055
        const int lp = k >> 4, rem = k & 15;
        const int tp = (rem < 8) ? 0 : 257;
        off = ((size_t)lp * XT_TP + tp) * 64 + (size_t)(rem & 7) * 8;
      }
      *(short8*)(base + off) = z;
    }
  }
}

// ---------------------------------------------------------------------------
// Main conv: per (b,l) block, 256x64 GEMM over K=576 = 9 taps x 64.
// global_load_lds double-buffered LDS staging (T3-minimum 2-phase): per tap,
// stage A[256][64] (32 KB, contiguous strip of padded xT) + B[64][64] (8 KB).
// XOR-swizzled LDS layout via pre-swizzled GLOBAL source (m173 rule):
// LDS[m][slot s] holds global slot s^(m&7); reads use slot ((kb*4+lg)^(lc&7)).
// 4 waves x (4 m-frags x 4 n-frags) mfma_f32_16x16x32_bf16; one barrier/tap.
// Epilogue: bias, float4 store, fused per-channel sum/sumsq (sm reuses lds).
// ---------------------------------------------------------------------------
__global__ __launch_bounds__(256, 2) void conv_mfma(
    const unsigned short* __restrict__ xT, const unsigned short* __restrict__ wT2,
    const float* __restrict__ bias, float* __restrict__ out,
    float* __restrict__ part) {
  const int orig = blockIdx.x;                   // 0..511
  const int wg = (orig & 7) * 64 + (orig >> 3);  // XCD x -> batch b = x (L2 locality)
  const int b = wg >> 6, l = wg & 63;
  const int tid = threadIdx.x;
  const int wid = tid >> 6, ln = tid & 63;
  const int lc = ln & 15, lg = ln >> 4;
  const int m0 = wid * 64;

  // [buf][ A: 16384 elems (32 KB) | B: 4096 elems (8 KB) ] -> 80 KB total
  __shared__ unsigned short lds[2][20480];

  // per-lane pre-swizzled source offset (elems): dst row-sub ln>>3, dst slot
  // ln&7 takes global slot (ln&7)^(ln>>3) of row (chunk*8 + (ln>>3))
  const int src_lane_off = ((ln >> 3) << 6) + ((((ln & 7) ^ (ln >> 3))) << 3);

  const unsigned short* xBase = xT + (size_t)(b * XT_LP + l) * XT_LSTRIDE + src_lane_off;
  const unsigned short* wBase = wT2 + (size_t)l * 9 * 4096 + src_lane_off;

  auto STAGE = [&](int buf, int tap) {
    const int i = tap / 3, j = tap - i * 3;
    const unsigned short* Ab = xBase + (size_t)i * XT_LSTRIDE + j * 64;
    unsigned short* La = &lds[buf][0];
#pragma unroll
    for (int q = 0; q < 8; ++q) {
      const int ch = wid * 8 + q;
      gload_lds16(Ab + ch * 512, La + ch * 512);
    }
    const unsigned short* Bb = wBase + (size_t)tap * 4096;
    unsigned short* Lb = &lds[buf][16384];
#pragma unroll
    for (int q = 0; q < 2; ++q) {
      const int ch = wid * 2 + q;
      gload_lds16(Bb + ch * 512, Lb + ch * 512);
    }
  };

  f32x4 acc[4][4] = {};

  STAGE(0, 0);
#pragma unroll
  for (int tap = 0; tap < 9; ++tap) {
    __syncthreads();  // implicit vmcnt(0)+lgkmcnt(0): stage(tap) landed, prior reads done
    if (tap + 1 < 9) STAGE((tap + 1) & 1, tap + 1);
    const unsigned short* La = &lds[tap & 1][0];
    const unsigned short* Lb = &lds[tap & 1][16384];
#pragma unroll
    for (int kb = 0; kb < 2; ++kb) {
      const int slot = (((kb * 4 + lg) ^ (lc & 7)) << 3);
      short8 af[4], bf[4];
#pragma unroll
      for (int mi = 0; mi < 4; ++mi)
        af[mi] = *(const short8*)(La + (m0 + mi * 16 + lc) * 64 + slot);
#pragma unroll
      for (int ni = 0; ni < 4; ++ni)
        bf[ni] = *(const short8*)(Lb + (ni * 16 + lc) * 64 + slot);
#pragma unroll
      for (int mi = 0; mi < 4; ++mi)
#pragma unroll
        for (int ni = 0; ni < 4; ++ni)
          acc[mi][ni] =
              __builtin_amdgcn_mfma_f32_16x16x32_bf16(af[mi], bf[ni], acc[mi][ni], 0, 0, 0);
    }
  }

  // epilogue: bias + store + fused stats. D: row(t)=m0+mi*16+lg*4+r, col(c)=ni*16+lc
  __syncthreads();
  float* sm = (float*)&lds[0][0];  // reuse main LDS: sm[(wid*4+ni)*32 + lc*2 + sel]
#pragma unroll
  for (int ni = 0; ni < 4; ++ni) {
    const int c = ni * 16 + lc;
    const float bv = bias[c * 64 + l];
    float s = 0.f, s2 = 0.f;
    float* op = out + ((size_t)(b * 64 + c) * 64 + l) * 256;
#pragma unroll
    for (int mi = 0; mi < 4; ++mi) {
      float4 vv;
#pragma unroll
      for (int r = 0; r < 4; ++r) {
        float v = acc[mi][ni][r] + bv;
        ((float*)&vv)[r] = v;
        s += v;
        s2 += v * v;
      }
      *(float4*)(op + m0 + mi * 16 + lg * 4) = vv;
    }
    s += __shfl_xor(s, 16);  s += __shfl_xor(s, 32);
    s2 += __shfl_xor(s2, 16); s2 += __shfl_xor(s2, 32);
    if (lg == 0) { sm[(wid * 4 + ni) * 32 + lc * 2] = s; sm[(wid * 4 + ni) * 32 + lc * 2 + 1] = s2; }
  }
  __syncthreads();
  if (tid < 128) {
    const int sel = tid >> 6, cc = tid & 63;
    const int ni = cc >> 4, lc2 = cc & 15;
    float r = 0.f;
#pragma unroll
    for (int w2 = 0; w2 < 4; ++w2) r += sm[(w2 * 4 + ni) * 32 + lc2 * 2 + sel];
    part[(size_t)wg * 128 + sel * 64 + cc] = r;
  }
}

// ---------------------------------------------------------------------------
// Finalize per-channel scale/shift from 512 block-partials.
// ---------------------------------------------------------------------------
__global__ __launch_bounds__(256) void stats_final_mf(
    const float* __restrict__ part, const float* __restrict__ gamma,
    const float* __restrict__ beta, float* __restrict__ ss) {
  const int c = blockIdx.x;  // 0..63
  const int tid = threadIdx.x;
  float s = 0.f, s2 = 0.f;
  for (int blk = tid; blk < 512; blk += 256) {
    s += part[(size_t)blk * 128 + c];
    s2 += part[(size_t)blk * 128 + 64 + c];
  }
#pragma unroll
  for (int off = 32; off; off >>= 1) {
    s += __shfl_down(s, off);
    s2 += __shfl_down(s2, off);
  }
  __shared__ float r0[4], r1[4];
  const int wid = tid >> 6, lane = tid & 63;
  if (lane == 0) { r0[wid] = s; r1[wid] = s2; }
  __syncthreads();
  if (tid == 0) {
    float S = r0[0] + r0[1] + r0[2] + r0[3];
    float S2 = r1[0] + r1[1] + r1[2] + r1[3];
    const float inv_n = 1.0f / 131072.f;
    float mean = S * inv_n;
    float var = S2 * inv_n - mean * mean;
    float inv = rsqrtf(var + EPS_);
    float sc = gamma[c] * inv;
    ss[c] = sc;
    ss[64 + c] = beta[c] - mean * sc;
  }
}

// ---------------------------------------------------------------------------
// BN apply + PReLU, in place, float4 vectorized.
// ---------------------------------------------------------------------------
__global__ __launch_bounds__(256) void bn_prelu(
    float* __restrict__ out, const float* __restrict__ scaleshift,
    const float* __restrict__ alpha) {
  const float a = alpha[0];
  constexpr size_t N4 = (size_t)B_ * OUT_C_ * OUT_L_ * T_ / 4;  // 2097152
  float4* p = (float4*)out;
  for (size_t i = (size_t)blockIdx.x * 256 + threadIdx.x; i < N4;
       i += (size_t)gridDim.x * 256) {
    const int c = (int)((i >> 12) & 63);
    const float sc = scaleshift[c];
    const float sh = scaleshift[64 + c];
    float4 v = p[i];
    v.x = v.x * sc + sh; v.x = (v.x >= 0.f) ? v.x : a * v.x;
    v.y = v.y * sc + sh; v.y = (v.y >= 0.f) ? v.y : a * v.y;
    v.z = v.z * sc + sh; v.z = (v.z >= 0.f) ? v.z : a * v.z;
    v.w = v.w * sc + sh; v.w = (v.w >= 0.f) ? v.w : a * v.w;
    p[i] = v;
  }
}

// ======================= Fallback (round-2 VALU path) =======================
__global__ __launch_bounds__(256) void conv_fb(
    const float* __restrict__ x, const float* __restrict__ w,
    const float* __restrict__ bias, float* __restrict__ out,
    float* __restrict__ part) {
  const int bid = blockIdx.x;
  const int cg = bid & 3;
  const int l = (bid >> 2) & 63;
  const int b = bid >> 8;
  const int t = threadIdx.x;
  const int cbase = cg * 16;
  __shared__ float lw[576 * 16];
  for (int idx = t; idx < 576 * 16; idx += 256) {
    const int k = idx >> 4, cl = idx & 15;
    lw[idx] = w[((size_t)(k * OUT_C_ + cbase + cl)) * OUT_L_ + l];
  }
  __syncthreads();
  float acc[16];
#pragma unroll
  for (int c = 0; c < 16; ++c) acc[c] = 0.f;
  const bool l0 = (l >= 1), l2 = (l + 1 < IN_L_);
  const bool t0 = (t >= 1), t2 = (t + 1 < T_);
  for (int ic = 0; ic < IN_C_; ++ic) {
    const float* xr = x + (((size_t)(b * IN_C_ + ic)) * IN_L_ + l) * T_ + t;
    float xv[9];
    xv[0] = (l0 && t0) ? xr[-T_ - 1] : 0.f;
    xv[1] = l0 ? xr[-T_] : 0.f;
    xv[2] = (l0 && t2) ? xr[-T_ + 1] : 0.f;
    xv[3] = t0 ? xr[-1] : 0.f;
    xv[4] = xr[0];
    xv[5] = t2 ? xr[1] : 0.f;
    xv[6] = (l2 && t0) ? xr[T_ - 1] : 0.f;
    xv[7] = l2 ? xr[T_] : 0.f;
    xv[8] = (l2 && t2) ? xr[T_ + 1] : 0.f;
    const int base = ic * 9 * 16;
#pragma unroll
    for (int kk = 0; kk < 9; ++kk) {
      const float xvk = xv[kk];
      const float* wk = &lw[base + kk * 16];
#pragma unroll
      for (int c = 0; c < 16; ++c) acc[c] = fmaf(xvk, wk[c], acc[c]);
    }
  }
  const int wid = t >> 6, lane = t & 63;
  __shared__ float ls[4][16], ls2[4][16];
  const size_t obase = (((size_t)(b * OUT_C_ + cbase)) * OUT_L_ + l) * T_ + t;
#pragma unroll
  for (int c = 0; c < 16; ++c) {
    float v = acc[c] + bias[(cbase + c) * OUT_L_ + l];
    out[obase + (size_t)c * (OUT_L_ * T_)] = v;
    float s = v, s2 = v * v;
#pragma unroll
    for (int off = 32; off; off >>= 1) {
      s += __shfl_down(s, off);
      s2 += __shfl_down(s2, off);
    }
    if (lane == 0) { ls[wid][c] = s; ls2[wid][c] = s2; }
  }
  __syncthreads();
  if (t < 16) {
    part[(size_t)bid * 32 + t] = ls[0][t] + ls[1][t] + ls[2][t] + ls[3][t];
  } else if (t < 32) {
    const int c = t - 16;
    part[(size_t)bid * 32 + 16 + c] = ls2[0][c] + ls2[1][c] + ls2[2][c] + ls2[3][c];
  }
}

__global__ __launch_bounds__(64) void stats_final_fb(
    const float* __restrict__ part, const float* __restrict__ gamma,
    const float* __restrict__ beta, float* __restrict__ scaleshift) {
  const int C = blockIdx.x;
  const int cg = C >> 4, cloc = C & 15;
  const int t = threadIdx.x;
  float s = 0.f, s2 = 0.f;
  for (int i = t; i < 512; i += 64) {
    const int b = i >> 6, l = i & 63;
    const size_t idx = ((size_t)(b * 256 + l * 4 + cg)) * 32;
    s += part[idx + cloc];
    s2 += part[idx + 16 + cloc];
  }
#pragma unroll
  for (int off = 32; off; off >>= 1) {
    s += __shfl_down(s, off);
    s2 += __shfl_down(s2, off);
  }
  if (t == 0) {
    const float inv_n = 1.0f / (float)(B_ * OUT_L_ * T_);
    const float mean = s * inv_n;
    const float var = s2 * inv_n - mean * mean;
    const float inv = rsqrtf(var + EPS_);
    const float sc = gamma[C] * inv;
    scaleshift[C] = sc;
    scaleshift[64 + C] = beta[C] - mean * sc;
  }
}

extern "C" void kernel_launch(void* const* d_in, const int* in_sizes, int n_in,
                              void* d_out, int out_size, void* d_ws, size_t ws_size,
                              hipStream_t stream) {
  const float* x = (const float*)d_in[0];
  const float* w = (const float*)d_in[1];
  const float* bias = (const float*)d_in[2];
  const float* gamma = (const float*)d_in[3];
  const float* beta = (const float*)d_in[4];
  const float* alpha = (const float*)d_in[5];
  float* out = (float*)d_out;

  if (ws_size >= WS_NEED) {
    unsigned short* xT = (unsigned short*)d_ws;
    unsigned short* wT2 = (unsigned short*)((char*)d_ws + WT2_OFF_B);
    float* part = (float*)((char*)d_ws + PART_OFF_B);
    float* ssb = (float*)((char*)d_ws + SS_OFF_B);
    prep_kernel<<<dim3(1176), dim3(256), 0, stream>>>(x, w, xT, wT2);
    conv_mfma<<<dim3(512), dim3(256), 0, stream>>>(xT, wT2, bias, out, part);
    stats_final_mf<<<dim3(64), dim3(256), 0, stream>>>(part, gamma, beta, ssb);
    bn_prelu<<<dim3(2048), dim3(256), 0, stream>>>(out, ssb, alpha);
  } else {
    float* ws = (float*)d_ws;
    float* part = ws;
    float* ss = ws + 65536;
    conv_fb<<<dim3(B_ * OUT_L_ * 4), dim3(256), 0, stream>>>(x, w, bias, out, part);
    stats_final_fb<<<dim3(64), dim3(64), 0, stream>>>(part, gamma, beta, ss);
    bn_prelu<<<dim3(2048), dim3(256), 0, stream>>>(out, ss, alpha);
  }
}